// Round 5
// baseline (364.024 us; speedup 1.0000x reference)
//
#include <hip/hip_runtime.h>
#include <math.h>

#define N_NODES 50000
#define N_EDGES 800000
#define DIN 256
#define DHID 128
#define DOUT 64
// Padded CSR row stride. In-degree ~ Poisson(16); P(deg > 64) ~ 1e-19 -> safe.
#define CSTRIDE 64
#define ZROW N_NODES            // sentinel row (kept zero); sorts to row tail
#define HBLOCKS 256
#define HCHUNK (N_EDGES / HBLOCKS)     // 3125 exactly
#define HWORDS (N_NODES / 4)           // 12500 packed byte-counters per block

// ---------------- CSR build: histogram / prefix / LDS-atomic fill ----------------

// byte-packed LDS-privatized histogram (4 bins per u32). Per-block per-node
// counts <= total degree (~45-64) << 255 -> no byte carry.
__global__ void k_hist(const int* __restrict__ idx, unsigned int* __restrict__ partials) {
    __shared__ unsigned int h[HWORDS];
    int t = threadIdx.x;
    for (int w = t; w < HWORDS; w += 256) h[w] = 0u;
    __syncthreads();
    int base = blockIdx.x * HCHUNK;
    for (int i = t; i < HCHUNK; i += 256) {
        int s = idx[base + i];
        atomicAdd(&h[s >> 2], 1u << ((s & 3) << 3));
    }
    __syncthreads();
    unsigned int* outp = partials + (size_t)blockIdx.x * HWORDS;
    for (int w = t; w < HWORDS; w += 256) outp[w] = h[w];
}

// merged: deg_out = sum(pS) ; prefix/deg_in = scan(pD) ; norms ns/nd/cc.
// One thread owns 4 nodes (one packed word column).
__global__ void k_hpre(const unsigned int* __restrict__ pS,
                       const unsigned int* __restrict__ pD,
                       unsigned int* __restrict__ prefix,
                       int* __restrict__ deg_in,
                       float* __restrict__ ns, float* __restrict__ nd,
                       float* __restrict__ cc) {
    int wid = blockIdx.x * 256 + threadIdx.x;
    if (wid >= HWORDS) return;
    // out-degree byte-sum
    unsigned int o0 = 0, o1 = 0, o2 = 0, o3 = 0;
#pragma unroll 4
    for (int b = 0; b < HBLOCKS; ++b) {
        unsigned int w = pS[(size_t)b * HWORDS + wid];
        o0 += w & 0xffu; o1 += (w >> 8) & 0xffu;
        o2 += (w >> 16) & 0xffu; o3 += w >> 24;
    }
    // in-degree packed exclusive scan (totals <= 64, no byte carry)
    unsigned int run = 0;
    for (int b = 0; b < HBLOCKS; ++b) {
        unsigned int w = pD[(size_t)b * HWORDS + wid];
        prefix[(size_t)b * HWORDS + wid] = run;
        run += w;
    }
    unsigned int i0 = run & 0xffu, i1 = (run >> 8) & 0xffu;
    unsigned int i2 = (run >> 16) & 0xffu, i3 = run >> 24;
    int4 di; di.x = (int)i0; di.y = (int)i1; di.z = (int)i2; di.w = (int)i3;
    *(int4*)(deg_in + (wid << 2)) = di;

    unsigned int dov[4] = {o0, o1, o2, o3};
    unsigned int div_[4] = {i0, i1, i2, i3};
    float4 vns, vnd, vcc;
    float* pns = &vns.x; float* pnd = &vnd.x; float* pcc = &vcc.x;
#pragma unroll
    for (int q = 0; q < 4; ++q) {
        unsigned int a = dov[q] < 1u ? 1u : dov[q];
        unsigned int b = div_[q] < 1u ? 1u : div_[q];
        float fa = 1.0f / sqrtf((float)a);
        float fb = 1.0f / sqrtf((float)b);
        pns[q] = fa; pnd[q] = fb; pcc[q] = fa * fb;
    }
    *(float4*)(ns + (wid << 2)) = vns;
    *(float4*)(nd + (wid << 2)) = vnd;
    *(float4*)(cc + (wid << 2)) = vcc;
}

// fill csr using LDS atomics only: LDS starts at this block's packed prefix,
// atomicAdd returns the exact slot. Zero global atomics.
__global__ void k_fill(const int* __restrict__ src, const int* __restrict__ dst,
                       const unsigned int* __restrict__ prefix,
                       unsigned short* __restrict__ csr) {
    __shared__ unsigned int h[HWORDS];
    int t = threadIdx.x;
    const unsigned int* prow = prefix + (size_t)blockIdx.x * HWORDS;
    for (int w = t; w < HWORDS; w += 256) h[w] = prow[w];
    __syncthreads();
    int base = blockIdx.x * HCHUNK;
    for (int i = t; i < HCHUNK; i += 256) {
        int s = src[base + i], d = dst[base + i];
        int sh = (d & 3) << 3;
        unsigned int old = atomicAdd(&h[d >> 2], 1u << sh);
        int slot = (int)((old >> sh) & 0xffu);
        csr[(d << 6) + slot] = (unsigned short)s;
    }
}

// One wave per node: pad row with ZROW, bitonic-sort 64 entries ascending
// (ZROW = 50000 > any real index -> pads land at the tail), store back.
// Sorted rows make concurrent waves sweep x as a moving window -> L2 locality.
__global__ void k_sortpad(unsigned short* __restrict__ csr,
                          const int* __restrict__ deg_in) {
    int node = blockIdx.x * 4 + (threadIdx.x >> 6);   // grid = N/4 exactly
    int lane = threadIdx.x & 63;
    int deg = deg_in[node];
    int v = csr[(node << 6) + lane];
    if (lane >= deg) v = ZROW;
#pragma unroll
    for (int k = 2; k <= 64; k <<= 1) {
        for (int j = k >> 1; j > 0; j >>= 1) {
            int other = __shfl_xor(v, j);
            bool up = ((lane & k) == 0);
            bool lower = ((lane & j) == 0);
            int mn = v < other ? v : other;
            int mx = v < other ? other : v;
            v = (lower == up) ? mn : mx;
        }
    }
    csr[(node << 6) + lane] = (unsigned short)v;
}

// ---------------- weight folding + sentinel-row zeroing ----------------
// blocks 0..63: W13 = W1@W3 ; block 64: bb = b1@W3 ; block 65: zero sentinel rows

__global__ void k_weights(const float* __restrict__ W1, const float* __restrict__ b1,
                          const float* __restrict__ W3,
                          float* __restrict__ W13, float* __restrict__ bb,
                          float* __restrict__ Y0, float* __restrict__ Y1) {
    if (blockIdx.x == 65) {
        int t = threadIdx.x;
        if (t < DOUT) {
            Y0[((size_t)ZROW << 6) + t] = 0.f;
            Y1[((size_t)ZROW << 6) + t] = 0.f;
        }
        return;
    }
    if (blockIdx.x == 64) {
        int j = threadIdx.x;
        if (j < DOUT) {
            float s = 0.f;
            for (int k = 0; k < DHID; ++k) s += b1[k] * W3[k * DOUT + j];
            bb[j] = s;
        }
        return;
    }
    int idx = blockIdx.x * 256 + threadIdx.x;  // 16384 outputs
    int i = idx >> 6, j = idx & 63;
    float s = 0.f;
    for (int k = 0; k < DHID; ++k) s += W1[i * DHID + k] * W3[k * DOUT + j];
    W13[idx] = s;
}

// ---------------- dense GEMM: Y[50000,64] = ns ∘ (X[50000,256] @ W13[256,64]) ----------------

__global__ void k_gemm(const float* __restrict__ X, const float* __restrict__ W13,
                       const float* __restrict__ ns, float* __restrict__ Y) {
    __shared__ float As[16][68];   // [k][row], padded
    __shared__ float Bs[16][64];   // [k][col]
    int tid = threadIdx.x;
    int tx = tid & 15, ty = tid >> 4;
    int row0 = blockIdx.x * 64;
    float acc[4][4];
#pragma unroll
    for (int i = 0; i < 4; ++i)
#pragma unroll
        for (int j = 0; j < 4; ++j) acc[i][j] = 0.f;

    int lr = tid >> 2;            // 0..63 row within tile
    int lk = (tid & 3) << 2;      // 0,4,8,12
    int arow = row0 + lr;
    if (arow > N_NODES - 1) arow = N_NODES - 1;   // clamp: garbage rows never stored

    for (int k0 = 0; k0 < DIN; k0 += 16) {
        float4 a = *(const float4*)(X + (size_t)arow * DIN + k0 + lk);
        As[lk + 0][lr] = a.x; As[lk + 1][lr] = a.y;
        As[lk + 2][lr] = a.z; As[lk + 3][lr] = a.w;
        float4 b = *(const float4*)(W13 + (size_t)(k0 + (tid >> 4)) * DOUT + ((tid & 15) << 2));
        *(float4*)&Bs[tid >> 4][(tid & 15) << 2] = b;
        __syncthreads();
#pragma unroll
        for (int k = 0; k < 16; ++k) {
            float4 av = *(const float4*)&As[k][ty << 2];
            float4 bv = *(const float4*)&Bs[k][tx << 2];
            float ar[4] = {av.x, av.y, av.z, av.w};
            float br[4] = {bv.x, bv.y, bv.z, bv.w};
#pragma unroll
            for (int i = 0; i < 4; ++i)
#pragma unroll
                for (int j = 0; j < 4; ++j) acc[i][j] += ar[i] * br[j];
        }
        __syncthreads();
    }
#pragma unroll
    for (int i = 0; i < 4; ++i) {
        int row = row0 + (ty << 2) + i;
        if (row < N_NODES) {
            float nsr = ns[row];
            float4 o;
            o.x = acc[i][0] * nsr; o.y = acc[i][1] * nsr;
            o.z = acc[i][2] * nsr; o.w = acc[i][3] * nsr;
            *(float4*)(Y + (size_t)row * DOUT + (tx << 2)) = o;
        }
    }
}

// ---------------- pull-mode SpMM, D=64: one wave per node, lane = column ----------------
// csr rows sorted ascending + padded to multiple of 8 with ZROW (x[ZROW]=0):
// branchless 8-deep loop, 8 saddr gathers in flight; sorted sources give the
// concurrent waves a moving L2-resident window over x.
// MODE 0: y = c*acc + ns*bb[lane] ; MODE 1: y = c*acc ; MODE 2: y = nd*acc + b3[lane]

template <int MODE>
__global__ void k_spmm(const float* __restrict__ x, float* __restrict__ y,
                       const unsigned short* __restrict__ csr,
                       const int* __restrict__ cnt,
                       const float* __restrict__ c, const float* __restrict__ ns,
                       const float* __restrict__ nd,
                       const float* __restrict__ bb, const float* __restrict__ b3) {
    int node = blockIdx.x * 4 + (threadIdx.x >> 6);   // grid = N/4 exactly
    int lane = threadIdx.x & 63;
    int npad = (cnt[node] + 7) & ~7;
    int sv = csr[(node << 6) + lane];     // whole padded edge list, one 128B load
    const float* xl = x + lane;
    float acc = 0.f;
    for (int j = 0; j < npad; j += 8) {
        int a0 = __builtin_amdgcn_readlane(sv, j);
        int a1 = __builtin_amdgcn_readlane(sv, j + 1);
        int a2 = __builtin_amdgcn_readlane(sv, j + 2);
        int a3 = __builtin_amdgcn_readlane(sv, j + 3);
        int a4 = __builtin_amdgcn_readlane(sv, j + 4);
        int a5 = __builtin_amdgcn_readlane(sv, j + 5);
        int a6 = __builtin_amdgcn_readlane(sv, j + 6);
        int a7 = __builtin_amdgcn_readlane(sv, j + 7);
        float t0 = xl[(size_t)a0 << 6];
        float t1 = xl[(size_t)a1 << 6];
        float t2 = xl[(size_t)a2 << 6];
        float t3 = xl[(size_t)a3 << 6];
        float t4 = xl[(size_t)a4 << 6];
        float t5 = xl[(size_t)a5 << 6];
        float t6 = xl[(size_t)a6 << 6];
        float t7 = xl[(size_t)a7 << 6];
        acc += t0; acc += t1; acc += t2; acc += t3;
        acc += t4; acc += t5; acc += t6; acc += t7;
    }
    float r;
    if (MODE == 0)      r = c[node] * acc + ns[node] * bb[lane];
    else if (MODE == 1) r = c[node] * acc;
    else                r = nd[node] * acc + b3[lane];
    y[(node << 6) + lane] = r;
}

// ---------------- launcher ----------------

extern "C" void kernel_launch(void* const* d_in, const int* in_sizes, int n_in,
                              void* d_out, int out_size, void* d_ws, size_t ws_size,
                              hipStream_t stream) {
    const float* X   = (const float*)d_in[0];
    const int*   src = (const int*)d_in[1];
    const int*   dst = (const int*)d_in[2];
    const float* W1  = (const float*)d_in[3];
    const float* b1  = (const float*)d_in[4];
    const float* W3  = (const float*)d_in[5];
    const float* b3  = (const float*)d_in[6];
    float* out = (float*)d_out;

    char* ws = (char*)d_ws;
    size_t off = 0;
    auto alloc = [&](size_t bytes) -> void* {
        void* p = ws + off;
        off = (off + bytes + 255) & ~(size_t)255;
        return p;
    };
    // big buffers, time-multiplexed (stream order guarantees safety):
    //   bufA: partialsS (hist src) -> prefix -> Y1   (k_hpre reads pS col-wise
    //         then overwrites the same column with prefix: per-thread safe)
    //   bufB: partialsD (hist dst) -> Y0
    const size_t BIGSZ = (size_t)(N_NODES + 1) * DOUT * 4;   // >= HBLOCKS*HWORDS*4
    char* bufA = (char*)alloc(BIGSZ);
    char* bufB = (char*)alloc(BIGSZ);
    int*            deg_in  = (int*)alloc((size_t)N_NODES * 4);
    unsigned short* csr     = (unsigned short*)alloc((size_t)N_NODES * CSTRIDE * 2);
    float*          ns      = (float*)alloc((size_t)N_NODES * 4);
    float*          nd      = (float*)alloc((size_t)N_NODES * 4);
    float*          cc      = (float*)alloc((size_t)N_NODES * 4);
    float*          W13     = (float*)alloc((size_t)DIN * DOUT * 4);
    float*          bb      = (float*)alloc(DOUT * 4);

    unsigned int* pS   = (unsigned int*)bufA;   // src partial histograms
    unsigned int* pD   = (unsigned int*)bufB;   // dst partial histograms
    unsigned int* pref = (unsigned int*)bufA;   // per-(block,node) packed offsets
    float*        Y0   = (float*)bufB;
    float*        Y1   = (float*)bufA;

    const int hblk = (HWORDS + 255) / 256;    // 49

    k_hist<<<HBLOCKS, 256, 0, stream>>>(src, pS);
    k_hist<<<HBLOCKS, 256, 0, stream>>>(dst, pD);
    k_hpre<<<hblk, 256, 0, stream>>>(pS, pD, pref, deg_in, ns, nd, cc);
    k_fill<<<HBLOCKS, 256, 0, stream>>>(src, dst, pref, csr);   // pref dead after
    k_sortpad<<<N_NODES / 4, 256, 0, stream>>>(csr, deg_in);

    k_weights<<<66, 256, 0, stream>>>(W1, b1, W3, W13, bb, Y0, Y1);

    // Y0 = ns ∘ (X @ (W1@W3))
    k_gemm<<<(N_NODES + 63) / 64, 256, 0, stream>>>(X, W13, ns, Y0);

    // 6 propagation passes; bias bb injected in pass 1, b3 in pass 6
    k_spmm<0><<<N_NODES / 4, 256, 0, stream>>>(Y0, Y1, csr, deg_in, cc, ns, nd, bb, b3);
    k_spmm<1><<<N_NODES / 4, 256, 0, stream>>>(Y1, Y0, csr, deg_in, cc, ns, nd, bb, b3);
    k_spmm<1><<<N_NODES / 4, 256, 0, stream>>>(Y0, Y1, csr, deg_in, cc, ns, nd, bb, b3);
    k_spmm<1><<<N_NODES / 4, 256, 0, stream>>>(Y1, Y0, csr, deg_in, cc, ns, nd, bb, b3);
    k_spmm<1><<<N_NODES / 4, 256, 0, stream>>>(Y0, Y1, csr, deg_in, cc, ns, nd, bb, b3);
    k_spmm<2><<<N_NODES / 4, 256, 0, stream>>>(Y1, out, csr, deg_in, cc, ns, nd, bb, b3);
}